// Round 4
// baseline (120.127 us; speedup 1.0000x reference)
//
#include <hip/hip_runtime.h>

// x: [16, 64, 256, 256] f32 in [0,255)
// out = x * ((floor(x/8) != dominant_bin[bc]) * mean[bc])
// dominant_bin from histc binning: clip(floor(x * 32/255), 0, 31), argmax first-tie.
//
// R3 changes:
//  - 1024 threads/block (one block per channel) -> 2 blocks/CU = 32 waves/CU
//    (100% wave occupancy; was 41%) to saturate the HBM read stream.
//  - skewed 32-replica LDS histogram (stride 33): bank = (rep+bin)&31, so
//    replicas of the same bin no longer collide in one bank.
//  - keep: pass-B L3-hot re-read + nontemporal output stores.

#define NBINS 32
#define HW 65536          // 256*256
#define NCHAN 1024        // 16*64
#define BT 1024           // threads per block
#define ITERS (HW / 4 / BT)   // 16 float4 per thread
#define NREP 32           // histogram replicas (per lane&31)
#define HSTRIDE 33        // skew: bank(rep*33+b) = (rep+b)&31

typedef float __attribute__((ext_vector_type(4))) fvec4;

__global__ __launch_bounds__(BT) void fused_colormoc_kernel(
    const float* __restrict__ x, float* __restrict__ out)
{
    __shared__ unsigned int hist[NREP * HSTRIDE];   // 4224 B
    __shared__ float ssum[BT / 64];                 // 16 wave sums
    __shared__ float s_mean;
    __shared__ int   s_dom;

    const int bc   = blockIdx.x;
    const int tid  = threadIdx.x;
    const int wave = tid >> 6;
    const int lane = tid & 63;
    const int rep  = tid & 31;

    // zero the 32*33 = 1056 counters
    hist[tid & 1023] = 0u;          // words 0..1023
    if (tid < NREP * HSTRIDE - 1024)
        hist[1024 + tid] = 0u;      // words 1024..1055
    __syncthreads();

    const fvec4* __restrict__ xp =
        (const fvec4*)(x + (size_t)bc * (size_t)HW);
    const float scale = 32.0f / 255.0f;   // same f32 constant as the reference
    unsigned int* __restrict__ h = &hist[rep * HSTRIDE];

    // ---- pass A: histogram + sum over this channel's 64K floats ----
    float sum = 0.0f;
    #pragma unroll
    for (int it = 0; it < ITERS; ++it) {
        fvec4 v = xp[it * BT + tid];
        sum += v.x + v.y + v.z + v.w;
        // x in [0,255): truncation == floor; clamp for histc edge safety
        int b0 = min(max((int)(v.x * scale), 0), NBINS - 1);
        int b1 = min(max((int)(v.y * scale), 0), NBINS - 1);
        int b2 = min(max((int)(v.z * scale), 0), NBINS - 1);
        int b3 = min(max((int)(v.w * scale), 0), NBINS - 1);
        atomicAdd(&h[b0], 1u);
        atomicAdd(&h[b1], 1u);
        atomicAdd(&h[b2], 1u);
        atomicAdd(&h[b3], 1u);
    }

    // wave reduce the sum (wave = 64 lanes)
    for (int off = 32; off > 0; off >>= 1)
        sum += __shfl_down(sum, off);
    if (lane == 0) ssum[wave] = sum;
    __syncthreads();

    // fold the 32 replicas: thread b (b<32) sums bin b across replicas
    if (tid < NBINS) {
        unsigned int c = 0u;
        #pragma unroll
        for (int r = 0; r < NREP; ++r) c += hist[r * HSTRIDE + tid];
        hist[tid] = c;   // reuse front of hist as folded histogram
    }
    __syncthreads();

    if (tid == 0) {
        // argmax with FIRST-occurrence tie-break (jnp.argmax semantics)
        int best = 0;
        unsigned int bestc = hist[0];
        #pragma unroll
        for (int i = 1; i < NBINS; ++i) {
            unsigned int c = hist[i];
            if (c > bestc) { bestc = c; best = i; }
        }
        s_dom = best;
        float s = 0.0f;
        #pragma unroll
        for (int w = 0; w < BT / 64; ++w) s += ssum[w];
        s_mean = s * (1.0f / (float)HW);
    }
    __syncthreads();

    const int   dm = s_dom;
    const float mn = s_mean;

    // ---- pass B: re-read (L3-hot), compute, nontemporal store ----
    fvec4* __restrict__ op = (fvec4*)(out + (size_t)bc * (size_t)HW);
    #pragma unroll
    for (int it = 0; it < ITERS; ++it) {
        fvec4 v = xp[it * BT + tid];
        fvec4 o;
        // x >= 0 so (int) truncation == floor; x/8 == x*0.125 exactly (pow2)
        o.x = ((int)(v.x * 0.125f) == dm) ? 0.0f : v.x * mn;
        o.y = ((int)(v.y * 0.125f) == dm) ? 0.0f : v.y * mn;
        o.z = ((int)(v.z * 0.125f) == dm) ? 0.0f : v.z * mn;
        o.w = ((int)(v.w * 0.125f) == dm) ? 0.0f : v.w * mn;
        // nontemporal: stream output past L3 (don't evict x's L3 footprint)
        __builtin_nontemporal_store(o, op + it * BT + tid);
    }
}

extern "C" void kernel_launch(void* const* d_in, const int* in_sizes, int n_in,
                              void* d_out, int out_size, void* d_ws, size_t ws_size,
                              hipStream_t stream) {
    const float* x = (const float*)d_in[0];
    float* out = (float*)d_out;

    fused_colormoc_kernel<<<NCHAN, BT, 0, stream>>>(x, out);
}